// Round 13
// baseline (257.848 us; speedup 1.0000x reference)
//
#include <hip/hip_runtime.h>
#include <hip/hip_bf16.h>

typedef __attribute__((ext_vector_type(8))) short sh8;
typedef __attribute__((ext_vector_type(8))) _Float16 h8;
typedef __attribute__((ext_vector_type(4))) float f4;
typedef unsigned short ushort_t;
typedef unsigned int uint_t;

// ---------- fast transcendentals (fp32) ----------
__device__ __forceinline__ float fast_rcp(float x) {
    return __builtin_amdgcn_rcpf(x);
}
__device__ __forceinline__ float sigmoidf_(float x) {
    return fast_rcp(1.f + __expf(-x));
}
__device__ __forceinline__ float tanhf_fast(float x) {
    float ax = fabsf(x);
    float e  = __expf(-2.f * ax);
    float t  = (1.f - e) * fast_rcp(1.f + e);
    return copysignf(t, x);
}

// ---------- bf16 split helpers ----------
__device__ __forceinline__ ushort_t bf16hi(float x) {
    return (ushort_t)(__float_as_uint(x) >> 16);
}
__device__ __forceinline__ float bf16tof(ushort_t u) {
    return __uint_as_float(((uint_t)u) << 16);
}

// ---------- fp16 helpers ----------
__device__ __forceinline__ ushort_t f2h(float x) {
    union { _Float16 f; ushort_t u; } cv;
    cv.f = (_Float16)x;
    return cv.u;
}
// XOR swizzle of 8-ushort blocks within a batch-row of sV
__device__ __forceinline__ int swzk(int k, int b) {
    return ((((k >> 3) ^ (b & 7)) << 3) | (k & 7));
}

// ---------- conv1 (1->10, 5x5 VALID) + maxpool2 + tanh ----------
// x: [B,784] as 28x28, out COMPACT: [B,144,10]
__global__ __launch_bounds__(256) void conv1_pool_tanh(
    const float* __restrict__ x, const float* __restrict__ w,
    const float* __restrict__ bias, float* __restrict__ out)
{
    __shared__ float sw[250];
    __shared__ float sb[10];
    int t = threadIdx.x;
    if (t < 250) sw[t] = w[t];
    if (t < 10)  sb[t] = bias[t];
    __syncthreads();

    int gp  = blockIdx.x * 256 + t;
    int b   = gp / 144;
    int pix = gp % 144;
    int py = pix / 12, px = pix % 12;

    const float* img = x + (long)b * 784 + (2 * py) * 28 + 2 * px;
    float r[6][6];
#pragma unroll
    for (int ry = 0; ry < 6; ++ry)
#pragma unroll
        for (int rx = 0; rx < 6; ++rx)
            r[ry][rx] = img[ry * 28 + rx];

    float* ob = out + ((long)b * 144 + pix) * 10;
    for (int oc = 0; oc < 10; ++oc) {
        float a0 = 0.f, a1 = 0.f, a2 = 0.f, a3 = 0.f;
#pragma unroll
        for (int ky = 0; ky < 5; ++ky)
#pragma unroll
            for (int kx = 0; kx < 5; ++kx) {
                float wv = sw[oc * 25 + ky * 5 + kx];
                a0 += wv * r[ky][kx];
                a1 += wv * r[ky][kx + 1];
                a2 += wv * r[ky + 1][kx];
                a3 += wv * r[ky + 1][kx + 1];
            }
        float m = fmaxf(fmaxf(a0, a1), fmaxf(a2, a3)) + sb[oc];
        ob[oc] = tanhf_fast(m);
    }
}

// ---------- row-wave fp16-MFMA 2D-LSTM, in-register epilogue ----------
// x compact [B, H*H, CIN]; Wx [5H,CIN], Whl/Whu [5H,HID], bias [5H];
// out compact [B, H*H, HID].  Block = 16 batches (grid 256), H waves.
// Wave w owns grid ROW w (cell (w, d-w) on step d). Weight rows are
// UNIT-MAJOR: row 4j+p (p=0..3: i,f1,f2,o) + g4 block at 4*HID+j; so the
// MFMA C-layout (col=batch, rows 4-per-lane) lands gates 0-3 of unit
// j=tt*4+lg directly in lane registers. Only g4 crosses lanes (tiny sG4).
// c_left in registers; c_up via parity sCup; sV parity-buffered ->
// reads parity d, writes parity d+1 -> ONE barrier per step.
template<int H, int HID, int CIN, int KV, int NK>
__global__ __launch_bounds__(H * 64, (H + 3) / 4) void mdlstm_row(
    const float* __restrict__ x, const float* __restrict__ Wx,
    const float* __restrict__ Whl, const float* __restrict__ Whu,
    const float* __restrict__ bias, float* __restrict__ out)
{
    constexpr int N    = H * H;
    constexpr int NT   = H * 64;
    constexpr int NB   = 16;
    constexpr int HL0  = CIN, HU0 = CIN + HID;
    constexpr int R03  = 4 * HID;           // unit-major gate0-3 rows
    constexpr int T03  = R03 / 16;          // tiles for gates 0-3
    constexpr int G4T  = (HID + 15) / 16;   // tiles for gate 4
    constexpr int TT   = T03 + G4T;
    constexpr int XTOT = H * NB * CIN;
    constexpr int XMAX = (XTOT + NT - 1) / NT;
    static_assert(R03 % 16 == 0, "gate0-3 rows tile-aligned");
    static_assert(NK * 32 == KV, "K chain covers KV");
    static_assert(KV >= CIN + 2 * HID, "K covers V");
    static_assert(2 * H * 16 * KV / 2 >= 5 * HID * HID, "praw fits in sV");

    __shared__ ushort_t sV[2][H][NB][KV];     // fp16 V, parity buffered
    __shared__ float    sCup[2][H][NB][HID];  // c_up relay, parity buffered
    __shared__ float    sG4[H][NB][HID];      // per-cell g4 exchange

    const int tid  = threadIdx.x;
    const int lane = tid & 63;
    const int w    = tid >> 6;               // wave = grid row
    const int lr   = lane & 15;              // batch / A-row-in-tile
    const int lg   = lane >> 4;              // k-group / C row-group
    const long bB  = (long)blockIdx.x * NB;

    // ---- A-frags (fp16, unit-major rows) via 3 whole-matrix rounds ----
    h8 Af[TT][NK];
#pragma unroll
    for (int tt = 0; tt < TT; ++tt)
#pragma unroll
        for (int ks = 0; ks < NK; ++ks)
#pragma unroll
            for (int e = 0; e < 8; ++e) Af[tt][ks][e] = (_Float16)0.f;

    float* praw = (float*)(&sV[0][0][0][0]);
    {   // round 1: Wx
        for (int idx = tid; idx < 5 * HID * CIN; idx += NT) praw[idx] = Wx[idx];
        __syncthreads();
#pragma unroll
        for (int tt = 0; tt < TT; ++tt) {
            int r = tt * 16 + lr;
            int o; bool valid;
            if (r < R03) { o = (r & 3) * HID + (r >> 2); valid = true; }
            else { int j = r - R03; valid = (j < HID); o = 4 * HID + j; }
            if (valid) {
#pragma unroll
                for (int ks = 0; ks < NK; ++ks)
#pragma unroll
                    for (int e = 0; e < 8; ++e) {
                        int k = ks * 32 + lg * 8 + e;
                        if (k < CIN) Af[tt][ks][e] = (_Float16)praw[o * CIN + k];
                    }
            }
        }
        __syncthreads();
    }
    {   // round 2: Whl
        for (int idx = tid; idx < 5 * HID * HID; idx += NT) praw[idx] = Whl[idx];
        __syncthreads();
#pragma unroll
        for (int tt = 0; tt < TT; ++tt) {
            int r = tt * 16 + lr;
            int o; bool valid;
            if (r < R03) { o = (r & 3) * HID + (r >> 2); valid = true; }
            else { int j = r - R03; valid = (j < HID); o = 4 * HID + j; }
            if (valid) {
#pragma unroll
                for (int ks = 0; ks < NK; ++ks)
#pragma unroll
                    for (int e = 0; e < 8; ++e) {
                        int kk = ks * 32 + lg * 8 + e - HL0;
                        if (kk >= 0 && kk < HID)
                            Af[tt][ks][e] = (_Float16)praw[o * HID + kk];
                    }
            }
        }
        __syncthreads();
    }
    {   // round 3: Whu
        for (int idx = tid; idx < 5 * HID * HID; idx += NT) praw[idx] = Whu[idx];
        __syncthreads();
#pragma unroll
        for (int tt = 0; tt < TT; ++tt) {
            int r = tt * 16 + lr;
            int o; bool valid;
            if (r < R03) { o = (r & 3) * HID + (r >> 2); valid = true; }
            else { int j = r - R03; valid = (j < HID); o = 4 * HID + j; }
            if (valid) {
#pragma unroll
                for (int ks = 0; ks < NK; ++ks)
#pragma unroll
                    for (int e = 0; e < 8; ++e) {
                        int kk = ks * 32 + lg * 8 + e - HU0;
                        if (kk >= 0 && kk < HID)
                            Af[tt][ks][e] = (_Float16)praw[o * HID + kk];
                    }
            }
        }
        __syncthreads();
    }

    // bias in remapped row order (C-in fragment)
    f4 biasF[TT];
#pragma unroll
    for (int tt = 0; tt < TT; ++tt)
#pragma unroll
        for (int q = 0; q < 4; ++q) {
            int r = tt * 16 + lg * 4 + q;
            float bv = 0.f;
            if (r < R03) bv = bias[(r & 3) * HID + (r >> 2)];
            else { int j = r - R03; if (j < HID) bv = bias[4 * HID + j]; }
            biasF[tt][q] = bv;
        }

    // ---- zero sV (both parities); stage x for cell (0,0) ----
    for (int idx = tid; idx < 2 * H * NB * KV; idx += NT)
        (&sV[0][0][0][0])[idx] = 0;
    __syncthreads();
    for (int idx = tid; idx < NB * CIN; idx += NT) {
        int b = idx / CIN, c = idx % CIN;
        sV[0][0][b][swzk(c, b)] = f2h(x[(bB + b) * (long)(N * CIN) + c]);
    }

    // ---- hoisted x-prefetch decomposition (absolute rows) ----
    int  xq_row[XMAX], xq_off[XMAX], xq_b[XMAX];
    long xq_gb[XMAX];
    bool xq_ok[XMAX];
#pragma unroll
    for (int q = 0; q < XMAX; ++q) {
        int idx = tid + q * NT;
        xq_ok[q] = (idx < XTOT);
        int rrow = 0, b = 0, c = 0;
        if (xq_ok[q]) { rrow = idx / (NB * CIN); int rem = idx % (NB * CIN);
                        b = rem / CIN; c = rem % CIN; }
        xq_row[q] = rrow; xq_b[q] = b;
        xq_off[q] = swzk(c, b);
        xq_gb[q]  = (bB + b) * (long)(N * CIN) + c;
    }

    float creg[T03];
#pragma unroll
    for (int tt = 0; tt < T03; ++tt) creg[tt] = 0.f;
    float* outb = out + (bB + lr) * (long)(N * HID);
    __syncthreads();

    // ---- diagonal loop: ONE barrier per step ----
    for (int d = 0; d < 2 * H - 1; ++d) {
        const int par = d & 1;
        const int jc  = d - w;
        const bool act = (jc >= 0) && (jc < H);
        const int i0n = (d + 1 > H - 1) ? d + 1 - (H - 1) : 0;
        const int i1n = (d + 1 < H - 1) ? d + 1 : H - 1;
        const int ncn = (d + 1 < 2 * H - 1) ? (i1n - i0n + 1) : 0;

        // ===== Phase A: gates for own cell (fp16 MFMA) =====
        f4 acc[TT];
        if (act) {
            h8 Bh[NK];
#pragma unroll
            for (int ks = 0; ks < NK; ++ks) {
                const int bo = (((ks * 4 + lg) ^ (lr & 7)) << 3);
                Bh[ks] = *(const h8*)&sV[par][w][lr][bo];
            }
#pragma unroll
            for (int tt = 0; tt < TT; ++tt) {
                acc[tt] = __builtin_amdgcn_mfma_f32_16x16x32_f16(
                              Af[tt][0], Bh[0], biasF[tt], 0, 0, 0);
#pragma unroll
                for (int ks = 1; ks < NK; ++ks)
                    acc[tt] = __builtin_amdgcn_mfma_f32_16x16x32_f16(
                                  Af[tt][ks], Bh[ks], acc[tt], 0, 0, 0);
            }
        }

        // prefetch next diagonal's x into registers
        float xval[XMAX];
#pragma unroll
        for (int q = 0; q < XMAX; ++q)
            if (xq_ok[q] && (unsigned)(xq_row[q] - i0n) < (unsigned)ncn)
                xval[q] = x[xq_gb[q] +
                            (long)(xq_row[q] * H + (d + 1 - xq_row[q])) * CIN];

        // ===== Phase B: in-register epilogue =====
        if (act) {
            // exchange g4 through per-cell LDS (only cross-lane piece)
#pragma unroll
            for (int g = 0; g < G4T; ++g)
#pragma unroll
                for (int q = 0; q < 4; ++q) {
                    int u = g * 16 + lg * 4 + q;
                    if (u < HID) sG4[w][lr][u] = acc[T03 + g][q];
                }
#pragma unroll
            for (int tt = 0; tt < T03; ++tt) {
                const int j = tt * 4 + lg;
                float g4 = sG4[w][lr][j];
                float g0 = acc[tt][0], g1 = acc[tt][1];
                float g2 = acc[tt][2], g3 = acc[tt][3];
                float c_left = (jc > 0) ? creg[tt] : 0.f;
                float c_up   = (w > 0) ? sCup[par][w][lr][j] : 0.f;
                float cc = sigmoidf_(g1) * c_left + sigmoidf_(g2) * c_up
                         + sigmoidf_(g0) * tanhf_fast(g4);
                float hh = sigmoidf_(g3) * tanhf_fast(cc);
                creg[tt] = cc;
                if (w + 1 < H) sCup[par ^ 1][w + 1][lr][j] = cc;
                ushort_t hv = f2h(hh);
                if (jc + 1 < H) sV[par ^ 1][w][lr][swzk(HL0 + j, lr)] = hv;
                if (w + 1 < H)  sV[par ^ 1][w + 1][lr][swzk(HU0 + j, lr)] = hv;
                outb[(w * H + jc) * HID + j] = hh;
            }
        }
        // write prefetched x into next-parity V
#pragma unroll
        for (int q = 0; q < XMAX; ++q)
            if (xq_ok[q] && (unsigned)(xq_row[q] - i0n) < (unsigned)ncn)
                sV[par ^ 1][xq_row[q]][xq_b[q]][xq_off[q]] = f2h(xval[q]);
        __syncthreads();
    }
}

// ---------- prep: scatter conv2 weights into MFMA A-fragment layout ----------
__global__ __launch_bounds__(256) void prep_conv2_frags(
    const float* __restrict__ wt, short* __restrict__ wf)
{
    int id = blockIdx.x * 256 + threadIdx.x;   // over 25*2*64*8 = 25600
    if (id >= 25600) return;
    int e    = id & 7;
    int lane = (id >> 3) & 63;
    int m    = (id >> 9) & 1;
    int tt   = id >> 10;            // tx*5+ty
    int tx = tt / 5, ty = tt % 5;
    int c = lane & 15, kg = lane >> 4;
    int oc = m * 16 + c, ic = kg * 8 + e;
    float wv = (oc < 30 && ic < 20) ? wt[((oc * 20 + ic) * 5 + ty) * 5 + tx] : 0.f;
    ushort_t hi = bf16hi(wv);
    ushort_t lo = bf16hi(wv - bf16tof(hi));
    wf[(((tt * 2 + m) * 2 + 0) * 64 + lane) * 8 + e] = (short)hi;
    wf[(((tt * 2 + m) * 2 + 1) * 64 + lane) * 8 + e] = (short)lo;
}

// ---------- prep: scatter fc1 weights into MFMA A-fragment layout ----------
__global__ __launch_bounds__(256) void prep_fc1_frags(
    const float* __restrict__ w1, short* __restrict__ wf1)
{
    int id = blockIdx.x * 256 + threadIdx.x;   // over 7*20*2*64*8 = 143360
    if (id >= 143360) return;
    int e    = id & 7;
    int r    = id >> 3;
    int lane = r & 63;  r >>= 6;
    int h    = r & 1;   r >>= 1;
    int ks   = r % 20;
    int m    = r / 20;
    int o  = m * 16 + (lane & 15);
    int kp = ks * 32 + (lane >> 4) * 8 + e;
    int pix = kp / 40, hid = kp % 40;
    float wv = (o < 100) ? w1[o * 640 + hid * 16 + pix] : 0.f;
    ushort_t hi = bf16hi(wv);
    ushort_t v  = h ? (ushort_t)bf16hi(wv - bf16tof(hi)) : hi;
    wf1[id] = (short)v;
}

// ---------- conv2 stage helper: one float4 (4 channels of one pos) ----------
__device__ __forceinline__ void stage_f4(
    ushort_t (*Hi)[40], ushort_t (*Lo)[40], int f, float4 v)
{
    int pos = f / 5, q = f % 5;
    ushort_t h0 = bf16hi(v.x), h1 = bf16hi(v.y);
    ushort_t h2 = bf16hi(v.z), h3 = bf16hi(v.w);
    ushort_t l0 = bf16hi(v.x - bf16tof(h0));
    ushort_t l1 = bf16hi(v.y - bf16tof(h1));
    ushort_t l2 = bf16hi(v.z - bf16tof(h2));
    ushort_t l3 = bf16hi(v.w - bf16tof(h3));
    uint2 hp = { (uint_t)h0 | ((uint_t)h1 << 16), (uint_t)h2 | ((uint_t)h3 << 16) };
    uint2 lp = { (uint_t)l0 | ((uint_t)l1 << 16), (uint_t)l2 | ((uint_t)l3 << 16) };
    *(uint2*)&Hi[pos][q * 4] = hp;
    *(uint2*)&Lo[pos][q * 4] = lp;
}

// ---------- conv2 via tap-decomposed MFMA, 16 images/block ----------
__global__ __launch_bounds__(320, 2) void conv2_mfma(
    const float* __restrict__ in, const short* __restrict__ wf,
    const float* __restrict__ bias, float* __restrict__ out)
{
    constexpr int NIMG = 16;
    __shared__ ushort_t sHi[2][144][40];
    __shared__ ushort_t sLo[2][144][40];
    __shared__ float    sPart[5][2][4][16][20];
    __shared__ float    sB[30];

    const int tid  = threadIdx.x;
    const int lane = tid & 63;
    const int wid  = tid >> 6;          // = tx
    const int c    = lane & 15;
    const int kg   = lane >> 4;
    const long b0  = (long)blockIdx.x * NIMG;

    const sh8* wfv = (const sh8*)wf;
    sh8 Ah[5][2], Al[5][2];
#pragma unroll
    for (int ty = 0; ty < 5; ++ty)
#pragma unroll
        for (int m = 0; m < 2; ++m) {
            int base = (((wid * 5 + ty) * 2 + m) * 2) * 64 + lane;
            Ah[ty][m] = wfv[base];
            Al[ty][m] = wfv[base + 64];
        }

    for (int idx = tid; idx < 2 * 144 * 20; idx += 320) {
        int bb = idx / (144 * 20);
        int r  = idx % (144 * 20);
        int pos = r / 20, s = 20 + r % 20;
        sHi[bb][pos][s] = 0;
        sLo[bb][pos][s] = 0;
    }
    if (tid < 30) sB[tid] = bias[tid];

    {
        const float* p = in + b0 * 2880;
        float4 v0 = *(const float4*)(p + 4 * tid);
        float4 v1 = *(const float4*)(p + 4 * (tid + 320));
        float4 v2 = {0.f, 0.f, 0.f, 0.f};
        if (tid < 80) v2 = *(const float4*)(p + 4 * (tid + 640));
        stage_f4(sHi[0], sLo[0], tid, v0);
        stage_f4(sHi[0], sLo[0], tid + 320, v1);
        if (tid < 80) stage_f4(sHi[0], sLo[0], tid + 640, v2);
    }
    __syncthreads();

    const int y0 = c >> 3, x = c & 7;
    for (int img = 0; img < NIMG; ++img) {
        const int cb = img & 1;
        float4 v0, v1, v2;
        const bool have = (img + 1 < NIMG);
        if (have) {
            const float* p = in + (b0 + img + 1) * 2880;
            v0 = *(const float4*)(p + 4 * tid);
            v1 = *(const float4*)(p + 4 * (tid + 320));
            if (tid < 80) v2 = *(const float4*)(p + 4 * (tid + 640));
        }
#pragma unroll
        for (int p4 = 0; p4 < 4; ++p4) {
            const int pos = (2 * p4 + y0) * 12 + x + wid;
            const ushort_t* bh = &sHi[cb][pos][kg * 8];
            const ushort_t* bl = &sLo[cb][pos][kg * 8];
            f4 hh0 = {0.f,0.f,0.f,0.f}, hl0 = {0.f,0.f,0.f,0.f}, lh0 = {0.f,0.f,0.f,0.f};
            f4 hh1 = {0.f,0.f,0.f,0.f}, hl1 = {0.f,0.f,0.f,0.f}, lh1 = {0.f,0.f,0.f,0.f};
#pragma unroll
            for (int ks = 0; ks < 5; ++ks) {
                sh8 Bh = *(const sh8*)(bh + ks * 12 * 40);
                sh8 Bl = *(const sh8*)(bl + ks * 12 * 40);
                hh0 = __builtin_amdgcn_mfma_f32_16x16x32_bf16(Ah[ks][0], Bh, hh0, 0, 0, 0);
                hl0 = __builtin_amdgcn_mfma_f32_16x16x32_bf16(Ah[ks][0], Bl, hl0, 0, 0, 0);
                lh0 = __builtin_amdgcn_mfma_f32_16x16x32_bf16(Al[ks][0], Bh, lh0, 0, 0, 0);
                hh1 = __builtin_amdgcn_mfma_f32_16x16x32_bf16(Ah[ks][1], Bh, hh1, 0, 0, 0);
                hl1 = __builtin_amdgcn_mfma_f32_16x16x32_bf16(Ah[ks][1], Bl, hl1, 0, 0, 0);
                lh1 = __builtin_amdgcn_mfma_f32_16x16x32_bf16(Al[ks][1], Bh, lh1, 0, 0, 0);
            }
            f4 c0 = hh0 + hl0 + lh0;
            f4 c1 = hh1 + hl1 + lh1;
            *(f4*)&sPart[wid][0][p4][c][kg * 4] = c0;
            *(f4*)&sPart[wid][1][p4][c][kg * 4] = c1;
        }
        if (have) {
            stage_f4(sHi[cb ^ 1], sLo[cb ^ 1], tid, v0);
            stage_f4(sHi[cb ^ 1], sLo[cb ^ 1], tid + 320, v1);
            if (tid < 80) stage_f4(sHi[cb ^ 1], sLo[cb ^ 1], tid + 640, v2);
        }
        __syncthreads();
        for (int idx = tid; idx < 480; idx += 320) {
            int pix = idx / 30, oc = idx % 30;
            int m = oc >> 4, r = oc & 15;
            int py = pix >> 2, px = pix & 3;
            float vmax = -1e30f;
#pragma unroll
            for (int dy = 0; dy < 2; ++dy)
#pragma unroll
                for (int dx = 0; dx < 2; ++dx) {
                    int n = (2 * py + dy) * 8 + 2 * px + dx;
                    float s = 0.f;
#pragma unroll
                    for (int w = 0; w < 5; ++w)
                        s += sPart[w][m][n >> 4][n & 15][r];
                    vmax = fmaxf(vmax, s);
                }
            out[(b0 + img) * 480 + idx] = tanhf_fast(vmax + sB[oc]);
        }
        __syncthreads();
    }
}

// ---------- fused fc1(640->100)+tanh + fc2(100->10) + softmax ----------
__global__ __launch_bounds__(448) void fc_fused(
    const float* __restrict__ in, const short* __restrict__ wf1,
    const float* __restrict__ b1, const float* __restrict__ w2,
    const float* __restrict__ b2, float* __restrict__ out)
{
    constexpr int XS = 648;      // padded row stride (ushorts)
    __shared__ ushort_t sXh[16][XS];
    __shared__ ushort_t sXl[16][XS];
    __shared__ float    sG[16][116];
    __shared__ float    sF[16][101];
    __shared__ float    sW2[1000];
    __shared__ float    sB2[10];
    __shared__ float    sL[16][12];

    const int tid  = threadIdx.x;
    const int lane = tid & 63;
    const int wid  = tid >> 6;
    const int lr   = lane & 15;
    const int lg   = lane >> 4;
    const long b0  = (long)blockIdx.x * 16;

    for (int idx = tid; idx < 2560; idx += 448) {
        int flat = idx * 4;
        int row = flat / 640, col = flat % 640;
        float4 v = *(const float4*)(in + (b0 + row) * 640 + col);
        ushort_t h0 = bf16hi(v.x), h1 = bf16hi(v.y);
        ushort_t h2 = bf16hi(v.z), h3 = bf16hi(v.w);
        uint2 hp = { (uint_t)h0 | ((uint_t)h1 << 16), (uint_t)h2 | ((uint_t)h3 << 16) };
        ushort_t l0 = bf16hi(v.x - bf16tof(h0));
        ushort_t l1 = bf16hi(v.y - bf16tof(h1));
        ushort_t l2 = bf16hi(v.z - bf16tof(h2));
        ushort_t l3 = bf16hi(v.w - bf16tof(h3));
        uint2 lp = { (uint_t)l0 | ((uint_t)l1 << 16), (uint_t)l2 | ((uint_t)l3 << 16) };
        *(uint2*)&sXh[row][col] = hp;
        *(uint2*)&sXl[row][col] = lp;
    }
    for (int idx = tid; idx < 1000; idx += 448) sW2[idx] = w2[idx];
    if (tid < 10) sB2[tid] = b2[tid];

    f4 biasF;
#pragma unroll
    for (int q = 0; q < 4; ++q) {
        int rr = wid * 16 + lg * 4 + q;
        biasF[q] = (rr < 100) ? b1[rr] : 0.f;
    }
    __syncthreads();

    {
        const sh8* wfv = (const sh8*)wf1;
        f4 hh = biasF, hl = {0.f,0.f,0.f,0.f}, lh = {0.f,0.f,0.f,0.f};
#pragma unroll
        for (int ks = 0; ks < 20; ++ks) {
            int base = ((wid * 20 + ks) * 2) * 64 + lane;
            sh8 Ah = wfv[base];
            sh8 Al = wfv[base + 64];
            sh8 Bh = *(const sh8*)&sXh[lr][ks * 32 + lg * 8];
            sh8 Bl = *(const sh8*)&sXl[lr][ks * 32 + lg * 8];
            hh = __builtin_amdgcn_mfma_f32_16x16x32_bf16(Ah, Bh, hh, 0, 0, 0);
            hl = __builtin_amdgcn_mfma_f32_16x16x32_bf16(Ah, Bl, hl, 0, 0, 0);
            lh = __builtin_amdgcn_mfma_f32_16x16x32_bf16(Al, Bh, lh, 0, 0, 0);
        }
        f4 acc = hh + hl + lh;
        *(f4*)&sG[lr][wid * 16 + lg * 4] = acc;
    }
    __syncthreads();

    for (int idx = tid; idx < 1600; idx += 448) {
        int bb = idx / 100, o = idx % 100;
        sF[bb][o] = tanhf_fast(sG[bb][o]);
    }
    __syncthreads();

    if (tid < 160) {
        int o2 = tid >> 4, bb = tid & 15;
        const float* wr = &sW2[o2 * 100];
        float acc = sB2[o2];
        for (int k = 0; k < 100; ++k) acc += sF[bb][k] * wr[k];
        sL[bb][o2] = acc;
    }
    __syncthreads();

    if (tid < 16) {
        float lg10[10];
#pragma unroll
        for (int o = 0; o < 10; ++o) lg10[o] = sL[tid][o];
        float m = lg10[0];
#pragma unroll
        for (int o = 1; o < 10; ++o) m = fmaxf(m, lg10[o]);
        float s = 0.f;
#pragma unroll
        for (int o = 0; o < 10; ++o) { lg10[o] = __expf(lg10[o] - m); s += lg10[o]; }
        float inv = fast_rcp(s);
        float* ob = out + (b0 + tid) * 10;
#pragma unroll
        for (int o = 0; o < 10; ++o) ob[o] = lg10[o] * inv;
    }
}

extern "C" void kernel_launch(void* const* d_in, const int* in_sizes, int n_in,
                              void* d_out, int out_size, void* d_ws, size_t ws_size,
                              hipStream_t stream)
{
    const float* x    = (const float*)d_in[0];
    const float* c1w  = (const float*)d_in[1];
    const float* c1b  = (const float*)d_in[2];
    const float* m1Wx = (const float*)d_in[3];
    const float* m1Wl = (const float*)d_in[4];
    const float* m1Wu = (const float*)d_in[5];
    const float* m1b  = (const float*)d_in[6];
    const float* c2w  = (const float*)d_in[7];
    const float* c2b  = (const float*)d_in[8];
    const float* m2Wx = (const float*)d_in[9];
    const float* m2Wl = (const float*)d_in[10];
    const float* m2Wu = (const float*)d_in[11];
    const float* m2b  = (const float*)d_in[12];
    const float* f1w  = (const float*)d_in[13];
    const float* f1b  = (const float*)d_in[14];
    const float* f2w  = (const float*)d_in[15];
    const float* f2b  = (const float*)d_in[16];
    float* outp = (float*)d_out;

    char* ws = (char*)d_ws;
    float* a1 = (float*)ws;                 // [B,144,10] 23.6 MB
    float* h1 = (float*)(ws + 23592960);    // [B,144,20] 47.2 MB
    float* a2 = a1;                         // [B,16,30] 7.86 MB (reuse a1)
    short* wfrag  = (short*)(ws + 8388608); // 102 KB (dead-a1 region, > a2)
    short* wfrag1 = (short*)(ws + 9437184); // 286 KB (dead-a1 region)
    float* h2 = h1;                         // [B,16,40] reuse

    conv1_pool_tanh<<<2304, 256, 0, stream>>>(x, c1w, c1b, a1);
    // m1: H=12, HID=20, CIN=10, KV=64, NK=2 -> 768 thr, 12 row-waves
    mdlstm_row<12, 20, 10, 64, 2><<<256, 768, 0, stream>>>(
        a1, m1Wx, m1Wl, m1Wu, m1b, h1);
    prep_conv2_frags<<<100, 256, 0, stream>>>(c2w, wfrag);    // a1 dead now
    prep_fc1_frags<<<560, 256, 0, stream>>>(f1w, wfrag1);
    conv2_mfma<<<256, 320, 0, stream>>>(h1, wfrag, c2b, a2);
    // m2: H=4, HID=40, CIN=30, KV=128, NK=4 -> 256 thr, 4 row-waves
    mdlstm_row<4, 40, 30, 128, 4><<<256, 256, 0, stream>>>(
        a2, m2Wx, m2Wl, m2Wu, m2b, h2);
    fc_fused<<<256, 448, 0, stream>>>(h2, wfrag1, f1b, f2w, f2b, outp);
}

// Round 14
// 189.308 us; speedup vs baseline: 1.3621x; 1.3621x over previous
//
#include <hip/hip_runtime.h>
#include <hip/hip_bf16.h>

typedef __attribute__((ext_vector_type(8))) short sh8;
typedef __attribute__((ext_vector_type(8))) _Float16 h8;
typedef __attribute__((ext_vector_type(4))) float f4;
typedef unsigned short ushort_t;
typedef unsigned int uint_t;

// ---------- fast transcendentals (fp32) ----------
__device__ __forceinline__ float fast_rcp(float x) {
    return __builtin_amdgcn_rcpf(x);
}
__device__ __forceinline__ float sigmoidf_(float x) {
    return fast_rcp(1.f + __expf(-x));
}
__device__ __forceinline__ float tanhf_fast(float x) {
    float ax = fabsf(x);
    float e  = __expf(-2.f * ax);
    float t  = (1.f - e) * fast_rcp(1.f + e);
    return copysignf(t, x);
}

// ---------- bf16 split helpers ----------
__device__ __forceinline__ ushort_t bf16hi(float x) {
    return (ushort_t)(__float_as_uint(x) >> 16);
}
__device__ __forceinline__ float bf16tof(ushort_t u) {
    return __uint_as_float(((uint_t)u) << 16);
}

// ---------- fp16 helpers ----------
__device__ __forceinline__ ushort_t f2h(float x) {
    union { _Float16 f; ushort_t u; } cv;
    cv.f = (_Float16)x;
    return cv.u;
}
// XOR swizzle of 8-ushort blocks within a batch-row of sV
__device__ __forceinline__ int swzk(int k, int b) {
    return ((((k >> 3) ^ (b & 7)) << 3) | (k & 7));
}

// ---------- conv1 (1->10, 5x5 VALID) + maxpool2 + tanh ----------
// x: [B,784] as 28x28, out COMPACT: [B,144,10]
__global__ __launch_bounds__(256) void conv1_pool_tanh(
    const float* __restrict__ x, const float* __restrict__ w,
    const float* __restrict__ bias, float* __restrict__ out)
{
    __shared__ float sw[250];
    __shared__ float sb[10];
    int t = threadIdx.x;
    if (t < 250) sw[t] = w[t];
    if (t < 10)  sb[t] = bias[t];
    __syncthreads();

    int gp  = blockIdx.x * 256 + t;
    int b   = gp / 144;
    int pix = gp % 144;
    int py = pix / 12, px = pix % 12;

    const float* img = x + (long)b * 784 + (2 * py) * 28 + 2 * px;
    float r[6][6];
#pragma unroll
    for (int ry = 0; ry < 6; ++ry)
#pragma unroll
        for (int rx = 0; rx < 6; ++rx)
            r[ry][rx] = img[ry * 28 + rx];

    float* ob = out + ((long)b * 144 + pix) * 10;
    for (int oc = 0; oc < 10; ++oc) {
        float a0 = 0.f, a1 = 0.f, a2 = 0.f, a3 = 0.f;
#pragma unroll
        for (int ky = 0; ky < 5; ++ky)
#pragma unroll
            for (int kx = 0; kx < 5; ++kx) {
                float wv = sw[oc * 25 + ky * 5 + kx];
                a0 += wv * r[ky][kx];
                a1 += wv * r[ky][kx + 1];
                a2 += wv * r[ky + 1][kx];
                a3 += wv * r[ky + 1][kx + 1];
            }
        float m = fmaxf(fmaxf(a0, a1), fmaxf(a2, a3)) + sb[oc];
        ob[oc] = tanhf_fast(m);
    }
}

// ---------- diagonal-wavefront fp16-MFMA 2D-LSTM, fat waves ----------
// (r12 structure, proven; prolog reduced to 3 whole-matrix rounds)
template<int H, int HID, int CIN, int KV, int NK, int NWM, int CSPL, int TPW, int NB>
__global__ __launch_bounds__(NWM * CSPL * 64) void mdlstm_f16(
    const float* __restrict__ x, const float* __restrict__ Wx,
    const float* __restrict__ Whl, const float* __restrict__ Whu,
    const float* __restrict__ bias, float* __restrict__ out)
{
    constexpr int N    = H * H;
    constexpr int NT   = NWM * CSPL * 64;
    constexpr int HL0  = CIN, HU0 = CIN + HID;
    constexpr int SVS  = KV;
    constexpr int GS   = 5 * HID;
    constexpr int XTOT = H * NB * CIN;
    constexpr int XMAX = (XTOT + NT - 1) / NT;
    constexpr int EPT  = NB * HID;
    constexpr int CPB  = NT / EPT;
    static_assert(NWM * TPW * 16 >= 5 * HID, "tiles cover gate rows");
    static_assert(KV >= CIN + 2 * HID, "K covers V");
    static_assert(H * NB * GS >= 5 * HID * HID && H * NB * GS >= 5 * HID * CIN,
                  "whole matrix fits in sG scratch");
    static_assert(CPB >= 1, "epilogue coverage");

    __shared__ ushort_t sV[H][16][SVS];      // fp16 V
    __shared__ float    sG[H][NB][GS];       // gates [slot][batch][row]
    __shared__ float    sC[2][H][NB][HID];   // c-state, parity buffered

    const int tid  = threadIdx.x;
    const int lane = tid & 63;
    const int wid  = tid >> 6;
    const int mth  = wid % NWM;
    const int cs   = wid / NWM;
    const int lr   = lane & 15;
    const int lg   = lane >> 4;
    const long bB  = (long)blockIdx.x * NB;

    // ---- A-frags for TPW tiles (fp16): 3 whole-matrix staging rounds ----
    h8 Af[TPW][NK];
#pragma unroll
    for (int tt = 0; tt < TPW; ++tt)
#pragma unroll
        for (int ks = 0; ks < NK; ++ks)
#pragma unroll
            for (int e = 0; e < 8; ++e) Af[tt][ks][e] = (_Float16)0.f;

    float* praw = &sG[0][0][0];
    {   // round 1: Wx (k in [0, CIN))
        for (int idx = tid; idx < 5 * HID * CIN; idx += NT) praw[idx] = Wx[idx];
        __syncthreads();
#pragma unroll
        for (int tt = 0; tt < TPW; ++tt) {
            int rg = (mth * TPW + tt) * 16 + lr;
            if (rg < 5 * HID) {
#pragma unroll
                for (int ks = 0; ks < NK; ++ks)
#pragma unroll
                    for (int e = 0; e < 8; ++e) {
                        int k = ks * 32 + lg * 8 + e;
                        if (k < CIN) Af[tt][ks][e] = (_Float16)praw[rg * CIN + k];
                    }
            }
        }
        __syncthreads();
    }
    {   // round 2: Whl (k in [HL0, HL0+HID))
        for (int idx = tid; idx < 5 * HID * HID; idx += NT) praw[idx] = Whl[idx];
        __syncthreads();
#pragma unroll
        for (int tt = 0; tt < TPW; ++tt) {
            int rg = (mth * TPW + tt) * 16 + lr;
            if (rg < 5 * HID) {
#pragma unroll
                for (int ks = 0; ks < NK; ++ks)
#pragma unroll
                    for (int e = 0; e < 8; ++e) {
                        int kk = ks * 32 + lg * 8 + e - HL0;
                        if (kk >= 0 && kk < HID)
                            Af[tt][ks][e] = (_Float16)praw[rg * HID + kk];
                    }
            }
        }
        __syncthreads();
    }
    {   // round 3: Whu (k in [HU0, HU0+HID))
        for (int idx = tid; idx < 5 * HID * HID; idx += NT) praw[idx] = Whu[idx];
        __syncthreads();
#pragma unroll
        for (int tt = 0; tt < TPW; ++tt) {
            int rg = (mth * TPW + tt) * 16 + lr;
            if (rg < 5 * HID) {
#pragma unroll
                for (int ks = 0; ks < NK; ++ks)
#pragma unroll
                    for (int e = 0; e < 8; ++e) {
                        int kk = ks * 32 + lg * 8 + e - HU0;
                        if (kk >= 0 && kk < HID)
                            Af[tt][ks][e] = (_Float16)praw[rg * HID + kk];
                    }
            }
        }
        __syncthreads();
    }

    f4 biasF[TPW];
#pragma unroll
    for (int tt = 0; tt < TPW; ++tt)
#pragma unroll
        for (int q = 0; q < 4; ++q) {
            int rr = (mth * TPW + tt) * 16 + lg * 4 + q;
            biasF[tt][q] = (rr < 5 * HID) ? bias[rr] : 0.f;
        }

    // ---- zero sV; stage x for cell (0,0) ----
    for (int idx = tid; idx < H * 16 * SVS; idx += NT) (&sV[0][0][0])[idx] = 0;
    __syncthreads();
    for (int idx = tid; idx < NB * CIN; idx += NT) {
        int b = idx / CIN, c = idx % CIN;
        sV[0][b][swzk(c, b)] = f2h(x[(bB + b) * (long)(N * CIN) + c]);
    }
    __syncthreads();

    // ---- hoisted epilogue mapping ----
    const bool ep_act = tid < CPB * EPT;
    const int  ep_ci0 = tid / EPT;
    const int  ep_b   = (tid % EPT) / HID;
    const int  ep_j   = tid % HID;
    const int  svl    = swzk(HL0 + ep_j, ep_b);
    const int  svu    = swzk(HU0 + ep_j, ep_b);
    float* outb = out + (bB + ep_b) * (long)(N * HID) + ep_j;

    // ---- hoisted x-prefetch decomposition ----
    int  xq_ci[XMAX], xq_b[XMAX], xq_off[XMAX];
    long xq_gb[XMAX];
    bool xq_ok[XMAX];
#pragma unroll
    for (int q = 0; q < XMAX; ++q) {
        int idx = tid + q * NT;
        xq_ok[q] = (idx < XTOT);
        int ci = 0, b = 0, c = 0;
        if (xq_ok[q]) { ci = idx / (NB * CIN); int rem = idx % (NB * CIN);
                        b = rem / CIN; c = rem % CIN; }
        xq_ci[q]  = ci; xq_b[q] = b;
        xq_off[q] = swzk(c, b);
        xq_gb[q]  = (bB + b) * (long)(N * CIN) + c;
    }

    // ---- diagonal loop ----
    for (int d = 0; d < 2 * H - 1; ++d) {
        const int i0  = (d > H - 1) ? d - (H - 1) : 0;
        const int i1  = (d < H - 1) ? d : H - 1;
        const int nc  = i1 - i0 + 1;
        const int i0n = (d + 1 > H - 1) ? d + 1 - (H - 1) : 0;
        const int i1n = (d + 1 < H - 1) ? d + 1 : H - 1;
        const int ncn = (d + 1 < 2 * H - 1) ? (i1n - i0n + 1) : 0;
        const int par = d & 1;

        // ===== Phase A: one V read per cell, TPW tile-chains =====
        for (int ci = cs; ci < nc; ci += CSPL) {
            h8 Bh[NK];
#pragma unroll
            for (int ks = 0; ks < NK; ++ks) {
                const int bo = (((ks * 4 + lg) ^ (lr & 7)) << 3);
                Bh[ks] = *(const h8*)&sV[ci][lr][bo];
            }
            f4 acc[TPW];
#pragma unroll
            for (int tt = 0; tt < TPW; ++tt) {
                acc[tt] = __builtin_amdgcn_mfma_f32_16x16x32_f16(
                              Af[tt][0], Bh[0], biasF[tt], 0, 0, 0);
#pragma unroll
                for (int ks = 1; ks < NK; ++ks)
                    acc[tt] = __builtin_amdgcn_mfma_f32_16x16x32_f16(
                                  Af[tt][ks], Bh[ks], acc[tt], 0, 0, 0);
            }
#pragma unroll
            for (int tt = 0; tt < TPW; ++tt) {
                int row4 = (mth * TPW + tt) * 16 + lg * 4;
                if (lr < NB && row4 + 4 <= 5 * HID)
                    *(f4*)&sG[ci][lr][row4] = acc[tt];
            }
        }

        // prefetch next diagonal's x (hides under MFMA)
        float xval[XMAX];
#pragma unroll
        for (int q = 0; q < XMAX; ++q)
            if (xq_ok[q] && xq_ci[q] < ncn) {
                int ii = i0n + xq_ci[q];
                xval[q] = x[xq_gb[q] + (long)(ii * H + (d + 1 - ii)) * CIN];
            }
        __syncthreads();

        // ===== Phase B: epilogue + scatter h/x into next-diag V =====
        if (ep_act) {
            for (int ci = ep_ci0; ci < nc; ci += CPB) {
                const int i = i0 + ci, jc = d - i;
                const float* gp = &sG[ci][ep_b][ep_j];
                float g0 = gp[0],       g1 = gp[HID],     g2 = gp[2 * HID];
                float g3 = gp[3 * HID], g4 = gp[4 * HID];
                float c_left = (jc > 0) ? sC[par][i][ep_b][ep_j] : 0.f;
                float c_up   = (i  > 0) ? sC[par][i - 1][ep_b][ep_j] : 0.f;
                float cc = sigmoidf_(g1) * c_left + sigmoidf_(g2) * c_up
                         + sigmoidf_(g0) * tanhf_fast(g4);
                float hh = sigmoidf_(g3) * tanhf_fast(cc);
                sC[par ^ 1][i][ep_b][ep_j] = cc;
                ushort_t hv = f2h(hh);
                if (jc + 1 < H) sV[i - i0n][ep_b][svl]     = hv;
                if (i + 1 < H)  sV[i + 1 - i0n][ep_b][svu] = hv;
                outb[(i * H + jc) * HID] = hh;
            }
        }
#pragma unroll
        for (int q = 0; q < XMAX; ++q)
            if (xq_ok[q] && xq_ci[q] < ncn)
                sV[xq_ci[q]][xq_b[q]][xq_off[q]] = f2h(xval[q]);
        __syncthreads();
    }
}

// ---------- prep: scatter conv2 weights into MFMA A-fragment layout ----------
__global__ __launch_bounds__(256) void prep_conv2_frags(
    const float* __restrict__ wt, short* __restrict__ wf)
{
    int id = blockIdx.x * 256 + threadIdx.x;   // over 25*2*64*8 = 25600
    if (id >= 25600) return;
    int e    = id & 7;
    int lane = (id >> 3) & 63;
    int m    = (id >> 9) & 1;
    int tt   = id >> 10;            // tx*5+ty
    int tx = tt / 5, ty = tt % 5;
    int c = lane & 15, kg = lane >> 4;
    int oc = m * 16 + c, ic = kg * 8 + e;
    float wv = (oc < 30 && ic < 20) ? wt[((oc * 20 + ic) * 5 + ty) * 5 + tx] : 0.f;
    ushort_t hi = bf16hi(wv);
    ushort_t lo = bf16hi(wv - bf16tof(hi));
    wf[(((tt * 2 + m) * 2 + 0) * 64 + lane) * 8 + e] = (short)hi;
    wf[(((tt * 2 + m) * 2 + 1) * 64 + lane) * 8 + e] = (short)lo;
}

// ---------- prep: scatter fc1 weights into MFMA A-fragment layout ----------
__global__ __launch_bounds__(256) void prep_fc1_frags(
    const float* __restrict__ w1, short* __restrict__ wf1)
{
    int id = blockIdx.x * 256 + threadIdx.x;   // over 7*20*2*64*8 = 143360
    if (id >= 143360) return;
    int e    = id & 7;
    int r    = id >> 3;
    int lane = r & 63;  r >>= 6;
    int h    = r & 1;   r >>= 1;
    int ks   = r % 20;
    int m    = r / 20;
    int o  = m * 16 + (lane & 15);
    int kp = ks * 32 + (lane >> 4) * 8 + e;
    int pix = kp / 40, hid = kp % 40;
    float wv = (o < 100) ? w1[o * 640 + hid * 16 + pix] : 0.f;
    ushort_t hi = bf16hi(wv);
    ushort_t v  = h ? (ushort_t)bf16hi(wv - bf16tof(hi)) : hi;
    wf1[id] = (short)v;
}

// ---------- conv2 stage helper: one float4 (4 channels of one pos) ----------
__device__ __forceinline__ void stage_f4(
    ushort_t (*Hi)[40], ushort_t (*Lo)[40], int f, float4 v)
{
    int pos = f / 5, q = f % 5;
    ushort_t h0 = bf16hi(v.x), h1 = bf16hi(v.y);
    ushort_t h2 = bf16hi(v.z), h3 = bf16hi(v.w);
    ushort_t l0 = bf16hi(v.x - bf16tof(h0));
    ushort_t l1 = bf16hi(v.y - bf16tof(h1));
    ushort_t l2 = bf16hi(v.z - bf16tof(h2));
    ushort_t l3 = bf16hi(v.w - bf16tof(h3));
    uint2 hp = { (uint_t)h0 | ((uint_t)h1 << 16), (uint_t)h2 | ((uint_t)h3 << 16) };
    uint2 lp = { (uint_t)l0 | ((uint_t)l1 << 16), (uint_t)l2 | ((uint_t)l3 << 16) };
    *(uint2*)&Hi[pos][q * 4] = hp;
    *(uint2*)&Lo[pos][q * 4] = lp;
}

// ---------- conv2 via tap-decomposed MFMA, 16 images/block ----------
__global__ __launch_bounds__(320, 2) void conv2_mfma(
    const float* __restrict__ in, const short* __restrict__ wf,
    const float* __restrict__ bias, float* __restrict__ out)
{
    constexpr int NIMG = 16;
    __shared__ ushort_t sHi[2][144][40];
    __shared__ ushort_t sLo[2][144][40];
    __shared__ float    sPart[5][2][4][16][20];
    __shared__ float    sB[30];

    const int tid  = threadIdx.x;
    const int lane = tid & 63;
    const int wid  = tid >> 6;          // = tx
    const int c    = lane & 15;
    const int kg   = lane >> 4;
    const long b0  = (long)blockIdx.x * NIMG;

    const sh8* wfv = (const sh8*)wf;
    sh8 Ah[5][2], Al[5][2];
#pragma unroll
    for (int ty = 0; ty < 5; ++ty)
#pragma unroll
        for (int m = 0; m < 2; ++m) {
            int base = (((wid * 5 + ty) * 2 + m) * 2) * 64 + lane;
            Ah[ty][m] = wfv[base];
            Al[ty][m] = wfv[base + 64];
        }

    for (int idx = tid; idx < 2 * 144 * 20; idx += 320) {
        int bb = idx / (144 * 20);
        int r  = idx % (144 * 20);
        int pos = r / 20, s = 20 + r % 20;
        sHi[bb][pos][s] = 0;
        sLo[bb][pos][s] = 0;
    }
    if (tid < 30) sB[tid] = bias[tid];

    {
        const float* p = in + b0 * 2880;
        float4 v0 = *(const float4*)(p + 4 * tid);
        float4 v1 = *(const float4*)(p + 4 * (tid + 320));
        float4 v2 = {0.f, 0.f, 0.f, 0.f};
        if (tid < 80) v2 = *(const float4*)(p + 4 * (tid + 640));
        stage_f4(sHi[0], sLo[0], tid, v0);
        stage_f4(sHi[0], sLo[0], tid + 320, v1);
        if (tid < 80) stage_f4(sHi[0], sLo[0], tid + 640, v2);
    }
    __syncthreads();

    const int y0 = c >> 3, x = c & 7;
    for (int img = 0; img < NIMG; ++img) {
        const int cb = img & 1;
        float4 v0, v1, v2;
        const bool have = (img + 1 < NIMG);
        if (have) {
            const float* p = in + (b0 + img + 1) * 2880;
            v0 = *(const float4*)(p + 4 * tid);
            v1 = *(const float4*)(p + 4 * (tid + 320));
            if (tid < 80) v2 = *(const float4*)(p + 4 * (tid + 640));
        }
#pragma unroll
        for (int p4 = 0; p4 < 4; ++p4) {
            const int pos = (2 * p4 + y0) * 12 + x + wid;
            const ushort_t* bh = &sHi[cb][pos][kg * 8];
            const ushort_t* bl = &sLo[cb][pos][kg * 8];
            f4 hh0 = {0.f,0.f,0.f,0.f}, hl0 = {0.f,0.f,0.f,0.f}, lh0 = {0.f,0.f,0.f,0.f};
            f4 hh1 = {0.f,0.f,0.f,0.f}, hl1 = {0.f,0.f,0.f,0.f}, lh1 = {0.f,0.f,0.f,0.f};
#pragma unroll
            for (int ks = 0; ks < 5; ++ks) {
                sh8 Bh = *(const sh8*)(bh + ks * 12 * 40);
                sh8 Bl = *(const sh8*)(bl + ks * 12 * 40);
                hh0 = __builtin_amdgcn_mfma_f32_16x16x32_bf16(Ah[ks][0], Bh, hh0, 0, 0, 0);
                hl0 = __builtin_amdgcn_mfma_f32_16x16x32_bf16(Ah[ks][0], Bl, hl0, 0, 0, 0);
                lh0 = __builtin_amdgcn_mfma_f32_16x16x32_bf16(Al[ks][0], Bh, lh0, 0, 0, 0);
                hh1 = __builtin_amdgcn_mfma_f32_16x16x32_bf16(Ah[ks][1], Bh, hh1, 0, 0, 0);
                hl1 = __builtin_amdgcn_mfma_f32_16x16x32_bf16(Ah[ks][1], Bl, hl1, 0, 0, 0);
                lh1 = __builtin_amdgcn_mfma_f32_16x16x32_bf16(Al[ks][1], Bh, lh1, 0, 0, 0);
            }
            f4 c0 = hh0 + hl0 + lh0;
            f4 c1 = hh1 + hl1 + lh1;
            *(f4*)&sPart[wid][0][p4][c][kg * 4] = c0;
            *(f4*)&sPart[wid][1][p4][c][kg * 4] = c1;
        }
        if (have) {
            stage_f4(sHi[cb ^ 1], sLo[cb ^ 1], tid, v0);
            stage_f4(sHi[cb ^ 1], sLo[cb ^ 1], tid + 320, v1);
            if (tid < 80) stage_f4(sHi[cb ^ 1], sLo[cb ^ 1], tid + 640, v2);
        }
        __syncthreads();
        for (int idx = tid; idx < 480; idx += 320) {
            int pix = idx / 30, oc = idx % 30;
            int m = oc >> 4, r = oc & 15;
            int py = pix >> 2, px = pix & 3;
            float vmax = -1e30f;
#pragma unroll
            for (int dy = 0; dy < 2; ++dy)
#pragma unroll
                for (int dx = 0; dx < 2; ++dx) {
                    int n = (2 * py + dy) * 8 + 2 * px + dx;
                    float s = 0.f;
#pragma unroll
                    for (int w = 0; w < 5; ++w)
                        s += sPart[w][m][n >> 4][n & 15][r];
                    vmax = fmaxf(vmax, s);
                }
            out[(b0 + img) * 480 + idx] = tanhf_fast(vmax + sB[oc]);
        }
        __syncthreads();
    }
}

// ---------- fused fc1(640->100)+tanh + fc2(100->10) + softmax ----------
__global__ __launch_bounds__(448) void fc_fused(
    const float* __restrict__ in, const short* __restrict__ wf1,
    const float* __restrict__ b1, const float* __restrict__ w2,
    const float* __restrict__ b2, float* __restrict__ out)
{
    constexpr int XS = 648;      // padded row stride (ushorts)
    __shared__ ushort_t sXh[16][XS];
    __shared__ ushort_t sXl[16][XS];
    __shared__ float    sG[16][116];
    __shared__ float    sF[16][101];
    __shared__ float    sW2[1000];
    __shared__ float    sB2[10];
    __shared__ float    sL[16][12];

    const int tid  = threadIdx.x;
    const int lane = tid & 63;
    const int wid  = tid >> 6;
    const int lr   = lane & 15;
    const int lg   = lane >> 4;
    const long b0  = (long)blockIdx.x * 16;

    for (int idx = tid; idx < 2560; idx += 448) {
        int flat = idx * 4;
        int row = flat / 640, col = flat % 640;
        float4 v = *(const float4*)(in + (b0 + row) * 640 + col);
        ushort_t h0 = bf16hi(v.x), h1 = bf16hi(v.y);
        ushort_t h2 = bf16hi(v.z), h3 = bf16hi(v.w);
        uint2 hp = { (uint_t)h0 | ((uint_t)h1 << 16), (uint_t)h2 | ((uint_t)h3 << 16) };
        ushort_t l0 = bf16hi(v.x - bf16tof(h0));
        ushort_t l1 = bf16hi(v.y - bf16tof(h1));
        ushort_t l2 = bf16hi(v.z - bf16tof(h2));
        ushort_t l3 = bf16hi(v.w - bf16tof(h3));
        uint2 lp = { (uint_t)l0 | ((uint_t)l1 << 16), (uint_t)l2 | ((uint_t)l3 << 16) };
        *(uint2*)&sXh[row][col] = hp;
        *(uint2*)&sXl[row][col] = lp;
    }
    for (int idx = tid; idx < 1000; idx += 448) sW2[idx] = w2[idx];
    if (tid < 10) sB2[tid] = b2[tid];

    f4 biasF;
#pragma unroll
    for (int q = 0; q < 4; ++q) {
        int rr = wid * 16 + lg * 4 + q;
        biasF[q] = (rr < 100) ? b1[rr] : 0.f;
    }
    __syncthreads();

    {
        const sh8* wfv = (const sh8*)wf1;
        f4 hh = biasF, hl = {0.f,0.f,0.f,0.f}, lh = {0.f,0.f,0.f,0.f};
#pragma unroll
        for (int ks = 0; ks < 20; ++ks) {
            int base = ((wid * 20 + ks) * 2) * 64 + lane;
            sh8 Ah = wfv[base];
            sh8 Al = wfv[base + 64];
            sh8 Bh = *(const sh8*)&sXh[lr][ks * 32 + lg * 8];
            sh8 Bl = *(const sh8*)&sXl[lr][ks * 32 + lg * 8];
            hh = __builtin_amdgcn_mfma_f32_16x16x32_bf16(Ah, Bh, hh, 0, 0, 0);
            hl = __builtin_amdgcn_mfma_f32_16x16x32_bf16(Ah, Bl, hl, 0, 0, 0);
            lh = __builtin_amdgcn_mfma_f32_16x16x32_bf16(Al, Bh, lh, 0, 0, 0);
        }
        f4 acc = hh + hl + lh;
        *(f4*)&sG[lr][wid * 16 + lg * 4] = acc;
    }
    __syncthreads();

    for (int idx = tid; idx < 1600; idx += 448) {
        int bb = idx / 100, o = idx % 100;
        sF[bb][o] = tanhf_fast(sG[bb][o]);
    }
    __syncthreads();

    if (tid < 160) {
        int o2 = tid >> 4, bb = tid & 15;
        const float* wr = &sW2[o2 * 100];
        float acc = sB2[o2];
        for (int k = 0; k < 100; ++k) acc += sF[bb][k] * wr[k];
        sL[bb][o2] = acc;
    }
    __syncthreads();

    if (tid < 16) {
        float lg10[10];
#pragma unroll
        for (int o = 0; o < 10; ++o) lg10[o] = sL[tid][o];
        float m = lg10[0];
#pragma unroll
        for (int o = 1; o < 10; ++o) m = fmaxf(m, lg10[o]);
        float s = 0.f;
#pragma unroll
        for (int o = 0; o < 10; ++o) { lg10[o] = __expf(lg10[o] - m); s += lg10[o]; }
        float inv = fast_rcp(s);
        float* ob = out + (b0 + tid) * 10;
#pragma unroll
        for (int o = 0; o < 10; ++o) ob[o] = lg10[o] * inv;
    }
}

extern "C" void kernel_launch(void* const* d_in, const int* in_sizes, int n_in,
                              void* d_out, int out_size, void* d_ws, size_t ws_size,
                              hipStream_t stream)
{
    const float* x    = (const float*)d_in[0];
    const float* c1w  = (const float*)d_in[1];
    const float* c1b  = (const float*)d_in[2];
    const float* m1Wx = (const float*)d_in[3];
    const float* m1Wl = (const float*)d_in[4];
    const float* m1Wu = (const float*)d_in[5];
    const float* m1b  = (const float*)d_in[6];
    const float* c2w  = (const float*)d_in[7];
    const float* c2b  = (const float*)d_in[8];
    const float* m2Wx = (const float*)d_in[9];
    const float* m2Wl = (const float*)d_in[10];
    const float* m2Wu = (const float*)d_in[11];
    const float* m2b  = (const float*)d_in[12];
    const float* f1w  = (const float*)d_in[13];
    const float* f1b  = (const float*)d_in[14];
    const float* f2w  = (const float*)d_in[15];
    const float* f2b  = (const float*)d_in[16];
    float* outp = (float*)d_out;

    char* ws = (char*)d_ws;
    float* a1 = (float*)ws;                 // [B,144,10] 23.6 MB
    float* h1 = (float*)(ws + 23592960);    // [B,144,20] 47.2 MB
    float* a2 = a1;                         // [B,16,30] 7.86 MB (reuse a1)
    short* wfrag  = (short*)(ws + 8388608); // 102 KB (dead-a1 region, > a2)
    short* wfrag1 = (short*)(ws + 9437184); // 286 KB (dead-a1 region)
    float* h2 = h1;                         // [B,16,40] reuse

    conv1_pool_tanh<<<2304, 256, 0, stream>>>(x, c1w, c1b, a1);
    // m1: H=12, HID=20, CIN=10, KV=64, NK=2, NWM=1, CSPL=12, TPW=7, NB=16
    mdlstm_f16<12, 20, 10, 64, 2, 1, 12, 7, 16><<<256, 768, 0, stream>>>(
        a1, m1Wx, m1Wl, m1Wu, m1b, h1);
    prep_conv2_frags<<<100, 256, 0, stream>>>(c2w, wfrag);    // a1 dead now
    prep_fc1_frags<<<560, 256, 0, stream>>>(f1w, wfrag1);
    conv2_mfma<<<256, 320, 0, stream>>>(h1, wfrag, c2b, a2);
    // m2: H=4, HID=40, CIN=30, KV=128, NK=4, NWM=3, CSPL=4, TPW=5, NB=16
    mdlstm_f16<4, 40, 30, 128, 4, 3, 4, 5, 16><<<256, 768, 0, stream>>>(
        a2, m2Wx, m2Wl, m2Wu, m2b, h2);
    fc_fused<<<256, 448, 0, stream>>>(h2, wfrag1, f1b, f2w, f2b, outp);
}

// Round 15
// 171.032 us; speedup vs baseline: 1.5076x; 1.1069x over previous
//
#include <hip/hip_runtime.h>
#include <hip/hip_bf16.h>

typedef __attribute__((ext_vector_type(8))) short sh8;
typedef __attribute__((ext_vector_type(8))) _Float16 h8;
typedef __attribute__((ext_vector_type(4))) float f4;
typedef unsigned short ushort_t;
typedef unsigned int uint_t;

// ---------- fast transcendentals (fp32) ----------
__device__ __forceinline__ float fast_rcp(float x) {
    return __builtin_amdgcn_rcpf(x);
}
__device__ __forceinline__ float sigmoidf_(float x) {
    return fast_rcp(1.f + __expf(-x));
}
__device__ __forceinline__ float tanhf_fast(float x) {
    float ax = fabsf(x);
    float e  = __expf(-2.f * ax);
    float t  = (1.f - e) * fast_rcp(1.f + e);
    return copysignf(t, x);
}

// ---------- fp16 helpers ----------
__device__ __forceinline__ ushort_t f2h(float x) {
    union { _Float16 f; ushort_t u; } cv;
    cv.f = (_Float16)x;
    return cv.u;
}
__device__ __forceinline__ float h2f(ushort_t u) {
    union { _Float16 f; ushort_t u; } cv;
    cv.u = u;
    return (float)cv.f;
}
// XOR swizzle of 8-ushort blocks within a batch-row of sV
__device__ __forceinline__ int swzk(int k, int b) {
    return ((((k >> 3) ^ (b & 7)) << 3) | (k & 7));
}

// ---------- conv1 (1->10, 5x5 VALID) + maxpool2 + tanh ----------
// x: [B,784] as 28x28, out COMPACT fp16: [B,144,10]
__global__ __launch_bounds__(256) void conv1_pool_tanh(
    const float* __restrict__ x, const float* __restrict__ w,
    const float* __restrict__ bias, ushort_t* __restrict__ out)
{
    __shared__ float sw[250];
    __shared__ float sb[10];
    int t = threadIdx.x;
    if (t < 250) sw[t] = w[t];
    if (t < 10)  sb[t] = bias[t];
    __syncthreads();

    int gp  = blockIdx.x * 256 + t;
    int b   = gp / 144;
    int pix = gp % 144;
    int py = pix / 12, px = pix % 12;

    const float* img = x + (long)b * 784 + (2 * py) * 28 + 2 * px;
    float r[6][6];
#pragma unroll
    for (int ry = 0; ry < 6; ++ry)
#pragma unroll
        for (int rx = 0; rx < 6; ++rx)
            r[ry][rx] = img[ry * 28 + rx];

    ushort_t* ob = out + ((long)b * 144 + pix) * 10;
    for (int oc = 0; oc < 10; ++oc) {
        float a0 = 0.f, a1 = 0.f, a2 = 0.f, a3 = 0.f;
#pragma unroll
        for (int ky = 0; ky < 5; ++ky)
#pragma unroll
            for (int kx = 0; kx < 5; ++kx) {
                float wv = sw[oc * 25 + ky * 5 + kx];
                a0 += wv * r[ky][kx];
                a1 += wv * r[ky][kx + 1];
                a2 += wv * r[ky + 1][kx];
                a3 += wv * r[ky + 1][kx + 1];
            }
        float m = fmaxf(fmaxf(a0, a1), fmaxf(a2, a3)) + sb[oc];
        ob[oc] = f2h(tanhf_fast(m));
    }
}

// ---------- diagonal-wavefront fp16-MFMA 2D-LSTM, fat waves ----------
// x compact fp16 [B, H*H, CIN]; Wx/Whl/Whu/bias fp32; out fp16 [B,H*H,HID].
template<int H, int HID, int CIN, int KV, int NK, int NWM, int CSPL, int TPW, int NB>
__global__ __launch_bounds__(NWM * CSPL * 64) void mdlstm_f16(
    const ushort_t* __restrict__ x, const float* __restrict__ Wx,
    const float* __restrict__ Whl, const float* __restrict__ Whu,
    const float* __restrict__ bias, ushort_t* __restrict__ out)
{
    constexpr int N    = H * H;
    constexpr int NT   = NWM * CSPL * 64;
    constexpr int HL0  = CIN, HU0 = CIN + HID;
    constexpr int SVS  = KV;
    constexpr int GS   = 5 * HID;
    constexpr int XTOT = H * NB * CIN;
    constexpr int XMAX = (XTOT + NT - 1) / NT;
    constexpr int EPT  = NB * HID;
    constexpr int CPB  = NT / EPT;
    static_assert(NWM * TPW * 16 >= 5 * HID, "tiles cover gate rows");
    static_assert(KV >= CIN + 2 * HID, "K covers V");
    static_assert(H * NB * GS >= 5 * HID * HID && H * NB * GS >= 5 * HID * CIN,
                  "whole matrix fits in sG scratch");
    static_assert(CPB >= 1, "epilogue coverage");

    __shared__ ushort_t sV[H][16][SVS];      // fp16 V
    __shared__ float    sG[H][NB][GS];       // gates [slot][batch][row]
    __shared__ float    sC[2][H][NB][HID];   // c-state, parity buffered

    const int tid  = threadIdx.x;
    const int lane = tid & 63;
    const int wid  = tid >> 6;
    const int mth  = wid % NWM;
    const int cs   = wid / NWM;
    const int lr   = lane & 15;
    const int lg   = lane >> 4;
    const long bB  = (long)blockIdx.x * NB;

    // ---- A-frags for TPW tiles (fp16): 3 whole-matrix staging rounds ----
    h8 Af[TPW][NK];
#pragma unroll
    for (int tt = 0; tt < TPW; ++tt)
#pragma unroll
        for (int ks = 0; ks < NK; ++ks)
#pragma unroll
            for (int e = 0; e < 8; ++e) Af[tt][ks][e] = (_Float16)0.f;

    float* praw = &sG[0][0][0];
    {   // round 1: Wx (k in [0, CIN))
        for (int idx = tid; idx < 5 * HID * CIN; idx += NT) praw[idx] = Wx[idx];
        __syncthreads();
#pragma unroll
        for (int tt = 0; tt < TPW; ++tt) {
            int rg = (mth * TPW + tt) * 16 + lr;
            if (rg < 5 * HID) {
#pragma unroll
                for (int ks = 0; ks < NK; ++ks)
#pragma unroll
                    for (int e = 0; e < 8; ++e) {
                        int k = ks * 32 + lg * 8 + e;
                        if (k < CIN) Af[tt][ks][e] = (_Float16)praw[rg * CIN + k];
                    }
            }
        }
        __syncthreads();
    }
    {   // round 2: Whl (k in [HL0, HL0+HID))
        for (int idx = tid; idx < 5 * HID * HID; idx += NT) praw[idx] = Whl[idx];
        __syncthreads();
#pragma unroll
        for (int tt = 0; tt < TPW; ++tt) {
            int rg = (mth * TPW + tt) * 16 + lr;
            if (rg < 5 * HID) {
#pragma unroll
                for (int ks = 0; ks < NK; ++ks)
#pragma unroll
                    for (int e = 0; e < 8; ++e) {
                        int kk = ks * 32 + lg * 8 + e - HL0;
                        if (kk >= 0 && kk < HID)
                            Af[tt][ks][e] = (_Float16)praw[rg * HID + kk];
                    }
            }
        }
        __syncthreads();
    }
    {   // round 3: Whu (k in [HU0, HU0+HID))
        for (int idx = tid; idx < 5 * HID * HID; idx += NT) praw[idx] = Whu[idx];
        __syncthreads();
#pragma unroll
        for (int tt = 0; tt < TPW; ++tt) {
            int rg = (mth * TPW + tt) * 16 + lr;
            if (rg < 5 * HID) {
#pragma unroll
                for (int ks = 0; ks < NK; ++ks)
#pragma unroll
                    for (int e = 0; e < 8; ++e) {
                        int kk = ks * 32 + lg * 8 + e - HU0;
                        if (kk >= 0 && kk < HID)
                            Af[tt][ks][e] = (_Float16)praw[rg * HID + kk];
                    }
            }
        }
        __syncthreads();
    }

    f4 biasF[TPW];
#pragma unroll
    for (int tt = 0; tt < TPW; ++tt)
#pragma unroll
        for (int q = 0; q < 4; ++q) {
            int rr = (mth * TPW + tt) * 16 + lg * 4 + q;
            biasF[tt][q] = (rr < 5 * HID) ? bias[rr] : 0.f;
        }

    // ---- zero sV; stage x for cell (0,0) ----
    for (int idx = tid; idx < H * 16 * SVS; idx += NT) (&sV[0][0][0])[idx] = 0;
    __syncthreads();
    for (int idx = tid; idx < NB * CIN; idx += NT) {
        int b = idx / CIN, c = idx % CIN;
        sV[0][b][swzk(c, b)] = x[(bB + b) * (long)(N * CIN) + c];
    }
    __syncthreads();

    // ---- hoisted epilogue mapping ----
    const bool ep_act = tid < CPB * EPT;
    const int  ep_ci0 = tid / EPT;
    const int  ep_b   = (tid % EPT) / HID;
    const int  ep_j   = tid % HID;
    const int  svl    = swzk(HL0 + ep_j, ep_b);
    const int  svu    = swzk(HU0 + ep_j, ep_b);
    ushort_t* outb = out + (bB + ep_b) * (long)(N * HID) + ep_j;

    // ---- hoisted x-prefetch decomposition ----
    int  xq_ci[XMAX], xq_b[XMAX], xq_off[XMAX];
    long xq_gb[XMAX];
    bool xq_ok[XMAX];
#pragma unroll
    for (int q = 0; q < XMAX; ++q) {
        int idx = tid + q * NT;
        xq_ok[q] = (idx < XTOT);
        int ci = 0, b = 0, c = 0;
        if (xq_ok[q]) { ci = idx / (NB * CIN); int rem = idx % (NB * CIN);
                        b = rem / CIN; c = rem % CIN; }
        xq_ci[q]  = ci; xq_b[q] = b;
        xq_off[q] = swzk(c, b);
        xq_gb[q]  = (bB + b) * (long)(N * CIN) + c;
    }

    // ---- diagonal loop ----
    for (int d = 0; d < 2 * H - 1; ++d) {
        const int i0  = (d > H - 1) ? d - (H - 1) : 0;
        const int i1  = (d < H - 1) ? d : H - 1;
        const int nc  = i1 - i0 + 1;
        const int i0n = (d + 1 > H - 1) ? d + 1 - (H - 1) : 0;
        const int i1n = (d + 1 < H - 1) ? d + 1 : H - 1;
        const int ncn = (d + 1 < 2 * H - 1) ? (i1n - i0n + 1) : 0;
        const int par = d & 1;

        // ===== Phase A: one V read per cell, TPW tile-chains =====
        for (int ci = cs; ci < nc; ci += CSPL) {
            h8 Bh[NK];
#pragma unroll
            for (int ks = 0; ks < NK; ++ks) {
                const int bo = (((ks * 4 + lg) ^ (lr & 7)) << 3);
                Bh[ks] = *(const h8*)&sV[ci][lr][bo];
            }
            f4 acc[TPW];
#pragma unroll
            for (int tt = 0; tt < TPW; ++tt) {
                acc[tt] = __builtin_amdgcn_mfma_f32_16x16x32_f16(
                              Af[tt][0], Bh[0], biasF[tt], 0, 0, 0);
#pragma unroll
                for (int ks = 1; ks < NK; ++ks)
                    acc[tt] = __builtin_amdgcn_mfma_f32_16x16x32_f16(
                                  Af[tt][ks], Bh[ks], acc[tt], 0, 0, 0);
            }
#pragma unroll
            for (int tt = 0; tt < TPW; ++tt) {
                int row4 = (mth * TPW + tt) * 16 + lg * 4;
                if (lr < NB && row4 + 4 <= 5 * HID)
                    *(f4*)&sG[ci][lr][row4] = acc[tt];
            }
        }

        // prefetch next diagonal's x (hides under MFMA)
        ushort_t xval[XMAX];
#pragma unroll
        for (int q = 0; q < XMAX; ++q)
            if (xq_ok[q] && xq_ci[q] < ncn) {
                int ii = i0n + xq_ci[q];
                xval[q] = x[xq_gb[q] + (long)(ii * H + (d + 1 - ii)) * CIN];
            }
        __syncthreads();

        // ===== Phase B: epilogue + scatter h/x into next-diag V =====
        if (ep_act) {
            for (int ci = ep_ci0; ci < nc; ci += CPB) {
                const int i = i0 + ci, jc = d - i;
                const float* gp = &sG[ci][ep_b][ep_j];
                float g0 = gp[0],       g1 = gp[HID],     g2 = gp[2 * HID];
                float g3 = gp[3 * HID], g4 = gp[4 * HID];
                float c_left = (jc > 0) ? sC[par][i][ep_b][ep_j] : 0.f;
                float c_up   = (i  > 0) ? sC[par][i - 1][ep_b][ep_j] : 0.f;
                float cc = sigmoidf_(g1) * c_left + sigmoidf_(g2) * c_up
                         + sigmoidf_(g0) * tanhf_fast(g4);
                float hh = sigmoidf_(g3) * tanhf_fast(cc);
                sC[par ^ 1][i][ep_b][ep_j] = cc;
                ushort_t hv = f2h(hh);
                if (jc + 1 < H) sV[i - i0n][ep_b][svl]     = hv;
                if (i + 1 < H)  sV[i + 1 - i0n][ep_b][svu] = hv;
                outb[(i * H + jc) * HID] = hv;
            }
        }
#pragma unroll
        for (int q = 0; q < XMAX; ++q)
            if (xq_ok[q] && xq_ci[q] < ncn)
                sV[xq_ci[q]][xq_b[q]][xq_off[q]] = xval[q];
        __syncthreads();
    }
}

// ---------- prep: conv2 weights -> fp16 wh/wl MFMA A-fragments ----------
__global__ __launch_bounds__(256) void prep_conv2_frags(
    const float* __restrict__ wt, short* __restrict__ wf)
{
    int id = blockIdx.x * 256 + threadIdx.x;   // over 25*2*64*8 = 25600
    if (id >= 25600) return;
    int e    = id & 7;
    int lane = (id >> 3) & 63;
    int m    = (id >> 9) & 1;
    int tt   = id >> 10;            // tx*5+ty
    int tx = tt / 5, ty = tt % 5;
    int c = lane & 15, kg = lane >> 4;
    int oc = m * 16 + c, ic = kg * 8 + e;
    float wv = (oc < 30 && ic < 20) ? wt[((oc * 20 + ic) * 5 + ty) * 5 + tx] : 0.f;
    ushort_t wh = f2h(wv);
    ushort_t wl = f2h(wv - h2f(wh));
    wf[(((tt * 2 + m) * 2 + 0) * 64 + lane) * 8 + e] = (short)wh;
    wf[(((tt * 2 + m) * 2 + 1) * 64 + lane) * 8 + e] = (short)wl;
}

// ---------- prep: fc1 weights -> fp16 wh/wl MFMA A-fragments ----------
__global__ __launch_bounds__(256) void prep_fc1_frags(
    const float* __restrict__ w1, short* __restrict__ wf1)
{
    int id = blockIdx.x * 256 + threadIdx.x;   // over 7*20*2*64*8 = 143360
    if (id >= 143360) return;
    int e    = id & 7;
    int r    = id >> 3;
    int lane = r & 63;  r >>= 6;
    int h    = r & 1;   r >>= 1;
    int ks   = r % 20;
    int m    = r / 20;
    int o  = m * 16 + (lane & 15);
    int kp = ks * 32 + (lane >> 4) * 8 + e;
    int pix = kp / 40, hid = kp % 40;
    float wv = (o < 100) ? w1[o * 640 + hid * 16 + pix] : 0.f;
    ushort_t wh = f2h(wv);
    ushort_t v  = h ? f2h(wv - h2f(wh)) : wh;
    wf1[id] = (short)v;
}

// ---------- conv2 via tap-decomposed MFMA, fp16 input, 16 images/block ----
// in COMPACT fp16 [B,144,20]; wf fp16 wh/wl frags; out fp16 [B,16,30].
__global__ __launch_bounds__(320, 2) void conv2_mfma(
    const ushort_t* __restrict__ in, const short* __restrict__ wf,
    const float* __restrict__ bias, ushort_t* __restrict__ out)
{
    constexpr int NIMG = 16;
    __shared__ ushort_t sImg[2][144][40];     // fp16; k 0..19 real, 20..39 zero
    __shared__ float    sPart[5][2][4][16][20];
    __shared__ float    sB[30];

    const int tid  = threadIdx.x;
    const int lane = tid & 63;
    const int wid  = tid >> 6;          // = tx
    const int c    = lane & 15;
    const int kg   = lane >> 4;
    const long b0  = (long)blockIdx.x * NIMG;

    const h8* wfv = (const h8*)wf;
    h8 Awh[5][2], Awl[5][2];
#pragma unroll
    for (int ty = 0; ty < 5; ++ty)
#pragma unroll
        for (int m = 0; m < 2; ++m) {
            int base = (((wid * 5 + ty) * 2 + m) * 2) * 64 + lane;
            Awh[ty][m] = wfv[base];
            Awl[ty][m] = wfv[base + 64];
        }

    // zero channel pads (both buffers, once)
    for (int idx = tid; idx < 2 * 144 * 20; idx += 320) {
        int bb = idx / (144 * 20);
        int r  = idx % (144 * 20);
        sImg[bb][r / 20][20 + r % 20] = 0;
    }
    if (tid < 30) sB[tid] = bias[tid];

    // stage image 0: 720 uint2 (4 ushorts each; 20%4==0 -> no pos crossing)
    {
        const ushort_t* p = in + b0 * 2880;
        uint2 u0 = *(const uint2*)(p + 4 * tid);
        uint2 u1 = *(const uint2*)(p + 4 * (tid + 320));
        uint2 u2 = {0, 0};
        if (tid < 80) u2 = *(const uint2*)(p + 4 * (tid + 640));
        {
            int g = 4 * tid;          *(uint2*)&sImg[0][g / 20][g % 20] = u0;
            g = 4 * (tid + 320);      *(uint2*)&sImg[0][g / 20][g % 20] = u1;
            if (tid < 80) { g = 4 * (tid + 640);
                            *(uint2*)&sImg[0][g / 20][g % 20] = u2; }
        }
    }
    __syncthreads();

    const int y0 = c >> 3, x = c & 7;
    for (int img = 0; img < NIMG; ++img) {
        const int cb = img & 1;
        uint2 u0, u1, u2;
        const bool have = (img + 1 < NIMG);
        if (have) {
            const ushort_t* p = in + (b0 + img + 1) * 2880;
            u0 = *(const uint2*)(p + 4 * tid);
            u1 = *(const uint2*)(p + 4 * (tid + 320));
            if (tid < 80) u2 = *(const uint2*)(p + 4 * (tid + 640));
        }
        // main: 4 pixel tiles; 4 independent chains (2 m-tiles x wh/wl)
#pragma unroll
        for (int p4 = 0; p4 < 4; ++p4) {
            const int pos = (2 * p4 + y0) * 12 + x + wid;
            const ushort_t* bh = &sImg[cb][pos][kg * 8];
            f4 aH0 = {0.f,0.f,0.f,0.f}, aL0 = {0.f,0.f,0.f,0.f};
            f4 aH1 = {0.f,0.f,0.f,0.f}, aL1 = {0.f,0.f,0.f,0.f};
#pragma unroll
            for (int ks = 0; ks < 5; ++ks) {
                h8 Bh = *(const h8*)(bh + ks * 12 * 40);
                aH0 = __builtin_amdgcn_mfma_f32_16x16x32_f16(Awh[ks][0], Bh, aH0, 0, 0, 0);
                aL0 = __builtin_amdgcn_mfma_f32_16x16x32_f16(Awl[ks][0], Bh, aL0, 0, 0, 0);
                aH1 = __builtin_amdgcn_mfma_f32_16x16x32_f16(Awh[ks][1], Bh, aH1, 0, 0, 0);
                aL1 = __builtin_amdgcn_mfma_f32_16x16x32_f16(Awl[ks][1], Bh, aL1, 0, 0, 0);
            }
            f4 c0 = aH0 + aL0;
            f4 c1 = aH1 + aL1;
            *(f4*)&sPart[wid][0][p4][c][kg * 4] = c0;
            *(f4*)&sPart[wid][1][p4][c][kg * 4] = c1;
        }
        if (have) {
            int g = 4 * tid;          *(uint2*)&sImg[cb ^ 1][g / 20][g % 20] = u0;
            g = 4 * (tid + 320);      *(uint2*)&sImg[cb ^ 1][g / 20][g % 20] = u1;
            if (tid < 80) { g = 4 * (tid + 640);
                            *(uint2*)&sImg[cb ^ 1][g / 20][g % 20] = u2; }
        }
        __syncthreads();
        // fused cross-wave sum + bias + 2x2 maxpool + tanh
        for (int idx = tid; idx < 480; idx += 320) {
            int pix = idx / 30, oc = idx % 30;
            int m = oc >> 4, r = oc & 15;
            int py = pix >> 2, px = pix & 3;
            float vmax = -1e30f;
#pragma unroll
            for (int dy = 0; dy < 2; ++dy)
#pragma unroll
                for (int dx = 0; dx < 2; ++dx) {
                    int n = (2 * py + dy) * 8 + 2 * px + dx;
                    float s = 0.f;
#pragma unroll
                    for (int w = 0; w < 5; ++w)
                        s += sPart[w][m][n >> 4][n & 15][r];
                    vmax = fmaxf(vmax, s);
                }
            out[(b0 + img) * 480 + idx] = f2h(tanhf_fast(vmax + sB[oc]));
        }
        __syncthreads();
    }
}

// ---------- fused fc1(640->100)+tanh + fc2(100->10) + softmax ----------
// in COMPACT fp16 [B,640]; wf1 fp16 wh/wl frags; out fp32 [B,10].
__global__ __launch_bounds__(448) void fc_fused(
    const ushort_t* __restrict__ in, const short* __restrict__ wf1,
    const float* __restrict__ b1, const float* __restrict__ w2,
    const float* __restrict__ b2, float* __restrict__ out)
{
    constexpr int XS = 648;      // padded row stride (ushorts)
    __shared__ ushort_t sX[16][XS];
    __shared__ float    sG[16][116];
    __shared__ float    sF[16][101];
    __shared__ float    sW2[1000];
    __shared__ float    sB2[10];
    __shared__ float    sL[16][12];

    const int tid  = threadIdx.x;
    const int lane = tid & 63;
    const int wid  = tid >> 6;
    const int lr   = lane & 15;
    const int lg   = lane >> 4;
    const long b0  = (long)blockIdx.x * 16;

    // stage x tile: 2560 uint2 (4 ushorts; 640%4==0 -> no row crossing)
    for (int idx = tid; idx < 2560; idx += 448) {
        int flat = idx * 4;
        int row = flat / 640, col = flat % 640;
        *(uint2*)&sX[row][col] =
            *(const uint2*)(in + (b0 + row) * 640 + col);
    }
    for (int idx = tid; idx < 1000; idx += 448) sW2[idx] = w2[idx];
    if (tid < 10) sB2[tid] = b2[tid];

    f4 biasF;
#pragma unroll
    for (int q = 0; q < 4; ++q) {
        int rr = wid * 16 + lg * 4 + q;
        biasF[q] = (rr < 100) ? b1[rr] : 0.f;
    }
    __syncthreads();

    {
        const h8* wfv = (const h8*)wf1;
        f4 hh = biasF, ll = {0.f, 0.f, 0.f, 0.f};
#pragma unroll
        for (int ks = 0; ks < 20; ++ks) {
            int base = ((wid * 20 + ks) * 2) * 64 + lane;
            h8 Awh = wfv[base];
            h8 Awl = wfv[base + 64];
            h8 Bh  = *(const h8*)&sX[lr][ks * 32 + lg * 8];
            hh = __builtin_amdgcn_mfma_f32_16x16x32_f16(Awh, Bh, hh, 0, 0, 0);
            ll = __builtin_amdgcn_mfma_f32_16x16x32_f16(Awl, Bh, ll, 0, 0, 0);
        }
        f4 acc = hh + ll;
        *(f4*)&sG[lr][wid * 16 + lg * 4] = acc;
    }
    __syncthreads();

    for (int idx = tid; idx < 1600; idx += 448) {
        int bb = idx / 100, o = idx % 100;
        sF[bb][o] = tanhf_fast(sG[bb][o]);
    }
    __syncthreads();

    if (tid < 160) {
        int o2 = tid >> 4, bb = tid & 15;
        const float* wr = &sW2[o2 * 100];
        float acc = sB2[o2];
        for (int k = 0; k < 100; ++k) acc += sF[bb][k] * wr[k];
        sL[bb][o2] = acc;
    }
    __syncthreads();

    if (tid < 16) {
        float lg10[10];
#pragma unroll
        for (int o = 0; o < 10; ++o) lg10[o] = sL[tid][o];
        float m = lg10[0];
#pragma unroll
        for (int o = 1; o < 10; ++o) m = fmaxf(m, lg10[o]);
        float s = 0.f;
#pragma unroll
        for (int o = 0; o < 10; ++o) { lg10[o] = __expf(lg10[o] - m); s += lg10[o]; }
        float inv = fast_rcp(s);
        float* ob = out + (b0 + tid) * 10;
#pragma unroll
        for (int o = 0; o < 10; ++o) ob[o] = lg10[o] * inv;
    }
}

extern "C" void kernel_launch(void* const* d_in, const int* in_sizes, int n_in,
                              void* d_out, int out_size, void* d_ws, size_t ws_size,
                              hipStream_t stream)
{
    const float* x    = (const float*)d_in[0];
    const float* c1w  = (const float*)d_in[1];
    const float* c1b  = (const float*)d_in[2];
    const float* m1Wx = (const float*)d_in[3];
    const float* m1Wl = (const float*)d_in[4];
    const float* m1Wu = (const float*)d_in[5];
    const float* m1b  = (const float*)d_in[6];
    const float* c2w  = (const float*)d_in[7];
    const float* c2b  = (const float*)d_in[8];
    const float* m2Wx = (const float*)d_in[9];
    const float* m2Wl = (const float*)d_in[10];
    const float* m2Wu = (const float*)d_in[11];
    const float* m2b  = (const float*)d_in[12];
    const float* f1w  = (const float*)d_in[13];
    const float* f1b  = (const float*)d_in[14];
    const float* f2w  = (const float*)d_in[15];
    const float* f2b  = (const float*)d_in[16];
    float* outp = (float*)d_out;

    char* ws = (char*)d_ws;
    ushort_t* a1 = (ushort_t*)ws;                  // [B,144,10] fp16 11.8 MB
    ushort_t* h1 = (ushort_t*)(ws + 23592960);     // [B,144,20] fp16 23.6 MB
    ushort_t* a2 = a1;                             // [B,16,30] fp16 3.9 MB
    short* wfrag  = (short*)(ws + 8388608);        // 102 KB (dead-a1 region)
    short* wfrag1 = (short*)(ws + 9437184);        // 286 KB (dead-a1 region)
    ushort_t* h2 = h1;                             // [B,640] fp16 reuse

    conv1_pool_tanh<<<2304, 256, 0, stream>>>(x, c1w, c1b, a1);
    // m1: H=12, HID=20, CIN=10, KV=64, NK=2, NWM=1, CSPL=12, TPW=7, NB=16
    mdlstm_f16<12, 20, 10, 64, 2, 1, 12, 7, 16><<<256, 768, 0, stream>>>(
        a1, m1Wx, m1Wl, m1Wu, m1b, h1);
    prep_conv2_frags<<<100, 256, 0, stream>>>(c2w, wfrag);    // a1 dead now
    prep_fc1_frags<<<560, 256, 0, stream>>>(f1w, wfrag1);
    conv2_mfma<<<256, 320, 0, stream>>>(h1, wfrag, c2b, a2);
    // m2: H=4, HID=40, CIN=30, KV=128, NK=4, NWM=3, CSPL=4, TPW=5, NB=16
    mdlstm_f16<4, 40, 30, 128, 4, 3, 4, 5, 16><<<256, 768, 0, stream>>>(
        a2, m2Wx, m2Wl, m2Wu, m2b, h2);
    fc_fused<<<256, 448, 0, stream>>>(h2, wfrag1, f1b, f2w, f2b, outp);
}